// Round 9
// baseline (507.111 us; speedup 1.0000x reference)
//
#include <hip/hip_runtime.h>

#define E_NUM 12000
#define D_DIM 6272
#define H_DIM 256
#define M1 24000

typedef __attribute__((ext_vector_type(8))) short short8;
typedef __attribute__((ext_vector_type(8))) __bf16 bf16x8;
typedef __attribute__((ext_vector_type(4))) float f32x4;

__device__ __forceinline__ float silu_f(float x) {
  return x / (1.0f + __expf(-x));
}

__device__ __forceinline__ bf16x8 ld_frag(const short* p) {
  return __builtin_bit_cast(bf16x8, *(const short8*)p);
}

__device__ __forceinline__ bf16x8 cvt8(f32x4 a, f32x4 b) {
  bf16x8 r;
#pragma unroll
  for (int j = 0; j < 4; ++j) {
    r[j] = (__bf16)a[j];
    r[4 + j] = (__bf16)b[j];
  }
  return r;
}

__device__ __forceinline__ void gll16(const void* g, void* l) {
  __builtin_amdgcn_global_load_lds(
      (const __attribute__((address_space(1))) void*)g,
      (__attribute__((address_space(3))) void*)l, 16, 0, 0);
}

// ---- P1 pack: P1[(kt*256 + col)*32 + p] = bf(W1[kt*32 + p][col]) ----
__global__ void pack_p1(const float* __restrict__ W1, short* __restrict__ P1) {
  const int kt = blockIdx.x;    // 0..195
  const int col = threadIdx.x;  // 0..255
  const float* src = W1 + (size_t)kt * 32 * H_DIM + col;
  short* dst = P1 + ((size_t)kt * H_DIM + col) * 32;
#pragma unroll
  for (int c = 0; c < 4; ++c) {
    short8 s;
#pragma unroll
    for (int j = 0; j < 8; ++j)
      s[j] = __builtin_bit_cast(short, (__bf16)src[(size_t)(c * 8 + j) * H_DIM]);
    *(short8*)(dst + c * 8) = s;
  }
}

// ---- P2 pack: P2[(kt*D_DIM + col)*32 + p] = bf(W2[kt*32 + p][col]) ----
__global__ void pack_p2(const float* __restrict__ W2, short* __restrict__ P2) {
  const int kt = blockIdx.y;                       // 0..7
  const int col = blockIdx.x * 128 + threadIdx.x;  // 0..6271
  const float* src = W2 + (size_t)kt * 32 * D_DIM + col;
  short* dst = P2 + ((size_t)kt * D_DIM + col) * 32;
#pragma unroll
  for (int c = 0; c < 4; ++c) {
    short8 s;
#pragma unroll
    for (int j = 0; j < 8; ++j)
      s[j] = __builtin_bit_cast(short, (__bf16)src[(size_t)(c * 8 + j) * D_DIM]);
    *(short8*)(dst + c * 8) = s;
  }
}

// ============== GEMM1 v9: true m97 clone. BM=64, BN=256, BK=32, A+B via gll ==============
// x = concat(node_embed, ori) [24000][6272] fp32; P1 [196][256][32] bf16.
// 4 waves, wave wn owns ALL 64 rows x 64 cols -> acc[4][4], 16 MFMA/iter. 196 iters.
// A LDS [64 rows][32 fp32]: 32B-granule g of row r stored at slot g^(r&3) (src-swizzled).
// B LDS [256 cols][32 bf16]: 16B-granule g of col c stored at slot g^(c&3) (src-swizzled).
#define G1_IT 196
__launch_bounds__(256, 3)
__global__ void gemm1_kernel(const float* __restrict__ node_embed,
                             const float* __restrict__ ori,
                             const float* __restrict__ x_edge_c,
                             const short* __restrict__ P1,
                             const float* __restrict__ b1,
                             short* __restrict__ hgp) {
  __shared__ __align__(16) float Als[2][64 * 32];  // 2 x 8 KB
  __shared__ __align__(16) short Bls[2][256 * 32]; // 2 x 16 KB

  const int t = threadIdx.x;
  const int wn = t >> 6;
  const int lane = t & 63;
  const int l15 = lane & 15;
  const int lq = lane >> 4;
  const int m_base = blockIdx.x * 64;

  // ---- A staging (2 gll rounds): round j: dest float idx t*4 + j*1024
  //      -> row (t>>3)+j*32, dest-granule (t>>1)&3, 16B-half t&1
  const int sr = t >> 3;
  const int sgl = ((t >> 1) & 3) ^ (sr & 3);  // source logical granule
  const int grow0 = m_base + sr;
  const int grow1 = m_base + sr + 32;
  const float* aAsrc = ((grow0 < E_NUM) ? node_embed + (size_t)grow0 * D_DIM
                                        : ori + (size_t)(grow0 - E_NUM) * D_DIM) +
                       sgl * 8 + (t & 1) * 4;
  const float* aBsrc = ((grow1 < E_NUM) ? node_embed + (size_t)grow1 * D_DIM
                                        : ori + (size_t)(grow1 - E_NUM) * D_DIM) +
                       sgl * 8 + (t & 1) * 4;

  // ---- B staging (4 gll rounds): round j: dest short idx t*8 + j*2048
  //      -> col (t>>2)+j*64, dest-granule t&3
  const int bct = t >> 2;
  const int bgl = (t & 3) ^ (bct & 3);
  const short* bsrc = P1 + (size_t)bct * 32 + bgl * 8;  // + it*8192 + j*2048

  const int axor = l15 & 3;  // frag granule slot = lq ^ axor

  f32x4 acc[4][4];
#pragma unroll
  for (int m = 0; m < 4; ++m)
#pragma unroll
    for (int n = 0; n < 4; ++n) acc[m][n] = (f32x4){0.f, 0.f, 0.f, 0.f};

  // prologue: stage tile 0 -> buf 0
  gll16(aAsrc, &Als[0][t * 4]);
  gll16(aBsrc, &Als[0][t * 4 + 1024]);
#pragma unroll
  for (int j = 0; j < 4; ++j) gll16(bsrc + j * 2048, &Bls[0][t * 8 + j * 2048]);
  __syncthreads();

  int cur = 0;
  for (int it = 0; it < G1_IT; ++it) {
    const int nxt = cur ^ 1;
    // stage tile it+1 (fire-and-forget; drains at end-of-iter barrier)
    if (it + 1 < G1_IT) {
      const float* aa = aAsrc + (size_t)(it + 1) * 32;
      const float* ab = aBsrc + (size_t)(it + 1) * 32;
      gll16(aa, &Als[nxt][t * 4]);
      gll16(ab, &Als[nxt][t * 4 + 1024]);
      const short* bs = bsrc + (size_t)(it + 1) * 8192;
#pragma unroll
      for (int j = 0; j < 4; ++j) gll16(bs + j * 2048, &Bls[nxt][t * 8 + j * 2048]);
    }
    // fragments from buf[cur]
    bf16x8 af[4];
    {
      const float* Ac = &Als[cur][0];
#pragma unroll
      for (int m = 0; m < 4; ++m) {
        const int ridx = (m * 16 + l15) * 32 + ((lq ^ axor) * 8);
        f32x4 lo = *(const f32x4*)(Ac + ridx);
        f32x4 hi = *(const f32x4*)(Ac + ridx + 4);
        af[m] = cvt8(lo, hi);
      }
    }
    bf16x8 bq[4];
#pragma unroll
    for (int n = 0; n < 4; ++n)
      bq[n] = ld_frag(&Bls[cur][(wn * 64 + n * 16 + l15) * 32 + ((lq ^ axor) * 8)]);
#pragma unroll
    for (int m = 0; m < 4; ++m)
#pragma unroll
      for (int n = 0; n < 4; ++n)
        acc[m][n] = __builtin_amdgcn_mfma_f32_16x16x32_bf16(af[m], bq[n], acc[m][n], 0, 0, 0);
    __syncthreads();
    cur = nxt;
  }

  // epilogue: bias + silu + gate -> hgp panel layout [8][24000][32]
#pragma unroll
  for (int n = 0; n < 4; ++n) {
    const int col = wn * 64 + n * 16 + l15;
    const float b1v = b1[col];
    const int panel = wn * 2 + (n >> 1);
    const int cin = (n & 1) * 16 + l15;
#pragma unroll
    for (int m = 0; m < 4; ++m) {
#pragma unroll
      for (int i = 0; i < 4; ++i) {
        const int gmr = m_base + m * 16 + lq * 4 + i;
        const int e = (gmr < E_NUM) ? gmr : gmr - E_NUM;
        float v = acc[m][n][i] + b1v;
        v = silu_f(v) * x_edge_c[(size_t)e * H_DIM + col];
        hgp[((size_t)panel * M1 + gmr) * 32 + cin] = __builtin_bit_cast(short, (__bf16)v);
      }
    }
  }
}

// ============== GEMM2 v7: m97 clone. 64e(+mirror) x 128d, BK=32, A+B via gll ==============
// out[e] = silu(hg[e]@W2+b2) + silu(hg[e+E]@W2+b2); A from hgp panels, B from P2.
// 4 waves, wave wd owns ALL 128 A-rows x 32 cols -> acc[8][2], 16 MFMA/iter. 8 iters.
__launch_bounds__(256, 4)
__global__ void gemm2_kernel(const short* __restrict__ hgp,
                             const short* __restrict__ P2,
                             const float* __restrict__ b2,
                             float* __restrict__ out) {
  __shared__ __align__(16) short Als2[2][128 * 32];  // 2 x 8 KB
  __shared__ __align__(16) short Bls2[2][128 * 32];  // 2 x 8 KB

  const int t = threadIdx.x;
  const int wd = t >> 6;  // wave -> 32 d-cols
  const int lane = t & 63;
  const int l15 = lane & 15;
  const int lq = lane >> 4;
  const int d0 = blockIdx.x * 128;
  const int e0 = blockIdx.y * 64;

  // staging coords: dest short idx t*8 (+ j*2048): row (t>>2)(+64j), dest-granule t&3
  const int sr = t >> 2;
  const int sgl = (t & 3) ^ (sr & 3);
  int eA = e0 + sr;
  if (eA >= E_NUM) eA = E_NUM - 1;  // clamped rows never stored
  const short* a0src = hgp + (size_t)eA * 32 + sgl * 8;            // + it*(M1*32)
  const short* a1src = hgp + (size_t)(E_NUM + eA) * 32 + sgl * 8;  // + it*(M1*32)
  const short* bsrc = P2 + (size_t)(d0 + sr) * 32 + sgl * 8;       // + it*(D_DIM*32), +j*2048

  const int axor = l15 & 3;

  f32x4 acc[8][2];
#pragma unroll
  for (int m = 0; m < 8; ++m)
#pragma unroll
    for (int n = 0; n < 2; ++n) acc[m][n] = (f32x4){0.f, 0.f, 0.f, 0.f};

  // prologue: stage k-tile 0
  gll16(a0src, &Als2[0][t * 8]);
  gll16(a1src, &Als2[0][t * 8 + 2048]);
  gll16(bsrc, &Bls2[0][t * 8]);
  gll16(bsrc + 2048, &Bls2[0][t * 8 + 2048]);
  __syncthreads();

  int cur = 0;
#pragma unroll
  for (int it = 0; it < 8; ++it) {
    const int nxt = cur ^ 1;
    if (it < 7) {
      const size_t ka = (size_t)(it + 1) * (M1 * 32);
      const size_t kb = (size_t)(it + 1) * ((size_t)D_DIM * 32);
      gll16(a0src + ka, &Als2[nxt][t * 8]);
      gll16(a1src + ka, &Als2[nxt][t * 8 + 2048]);
      gll16(bsrc + kb, &Bls2[nxt][t * 8]);
      gll16(bsrc + kb + 2048, &Bls2[nxt][t * 8 + 2048]);
    }
    bf16x8 bq[2];
#pragma unroll
    for (int n = 0; n < 2; ++n)
      bq[n] = ld_frag(&Bls2[cur][(wd * 32 + n * 16 + l15) * 32 + ((lq ^ axor) * 8)]);
#pragma unroll
    for (int m = 0; m < 8; ++m) {
      bf16x8 af = ld_frag(&Als2[cur][(m * 16 + l15) * 32 + ((lq ^ axor) * 8)]);
#pragma unroll
      for (int n = 0; n < 2; ++n)
        acc[m][n] = __builtin_amdgcn_mfma_f32_16x16x32_bf16(af, bq[n], acc[m][n], 0, 0, 0);
    }
    __syncthreads();
    cur = nxt;
  }

  // epilogue: bias + silu + combine halves -> fp32 out
#pragma unroll
  for (int n = 0; n < 2; ++n) {
    const int col = d0 + wd * 32 + n * 16 + l15;
    const float b2v = b2[col];
#pragma unroll
    for (int mm = 0; mm < 4; ++mm) {
#pragma unroll
      for (int i = 0; i < 4; ++i) {
        const int e = e0 + mm * 16 + lq * 4 + i;
        if (e < E_NUM) {
          out[(size_t)e * D_DIM + col] =
              silu_f(acc[mm][n][i] + b2v) + silu_f(acc[mm + 4][n][i] + b2v);
        }
      }
    }
  }
}

extern "C" void kernel_launch(void* const* d_in, const int* in_sizes, int n_in,
                              void* d_out, int out_size, void* d_ws, size_t ws_size,
                              hipStream_t stream) {
  const float* node_embed = (const float*)d_in[0];
  const float* x_edge_c = (const float*)d_in[1];
  const float* ori = (const float*)d_in[2];
  const float* W1 = (const float*)d_in[3];
  const float* b1 = (const float*)d_in[4];
  const float* W2 = (const float*)d_in[5];
  const float* b2 = (const float*)d_in[6];
  float* out_p = (float*)d_out;

  char* ws = (char*)d_ws;
  short* P1 = (short*)ws;                   // [196][256][32] bf16 = 3,211,264 B
  short* P2 = (short*)(ws + 3211264);       // [8][6272][32] bf16 = 3,211,264 B
  short* hgp = (short*)(ws + 2 * 3211264);  // [8][24000][32] bf16 = 12,288,000 B

  pack_p1<<<dim3(D_DIM / 32), 256, 0, stream>>>(W1, P1);
  pack_p2<<<dim3(D_DIM / 128, 8), 128, 0, stream>>>(W2, P2);

  gemm1_kernel<<<dim3(M1 / 64), 256, 0, stream>>>(node_embed, ori, x_edge_c, P1, b1, hgp);

  gemm2_kernel<<<dim3(D_DIM / 128, (E_NUM + 63) / 64), 256, 0, stream>>>(hgp, P2, b2, out_p);
}